// Round 9
// baseline (610.479 us; speedup 1.0000x reference)
//
#include <hip/hip_runtime.h>

#define NB 8
#define NS 1024
#define NH 32
#define NKV 8
#define ND 128
#define QT 128     // attn: per block 4 waves x 32 q-rows
#define KT 64

typedef _Float16 f16x8 __attribute__((ext_vector_type(8)));
typedef _Float16 f16x4 __attribute__((ext_vector_type(4)));
typedef __fp16 fp16x2 __attribute__((ext_vector_type(2)));
typedef float f32x16 __attribute__((ext_vector_type(16)));
typedef unsigned int u32x2 __attribute__((ext_vector_type(2)));

__device__ __forceinline__ float exp2fast(float x) { return __builtin_amdgcn_exp2f(x); }
__device__ __forceinline__ unsigned pkrtz_u(float a, float b) {
  union { fp16x2 h; unsigned u; } c;
  c.h = __builtin_amdgcn_cvt_pkrtz(a, b);
  return c.u;
}
__device__ __forceinline__ u32x2 swap32(float x) {
  union { float f; unsigned u; } c; c.f = x;
  return __builtin_amdgcn_permlane32_swap(c.u, c.u, false, false);
}
__device__ __forceinline__ float asf(unsigned u) { union { unsigned u; float f; } c; c.u = u; return c.f; }

// ---------------- pre-pass A: K f32 -> f16, [t][dkv] -> [b][hkv][kv][d] ----------------
__global__ __launch_bounds__(256)
void cvt_k(const float* __restrict__ kg, _Float16* __restrict__ kf)
{
  int g = blockIdx.x * 256 + threadIdx.x;       // float4 index, 8192*256 total
  int t  = g >> 8;
  int c4 = g & 255;
  int b  = t >> 10, kv = t & 1023;
  int hkv = c4 >> 5, d4 = (c4 & 31) * 4;
  float4 v = ((const float4*)kg)[g];
  union { f16x4 h; unsigned long long u; } p;
  p.h[0] = (_Float16)v.x; p.h[1] = (_Float16)v.y;
  p.h[2] = (_Float16)v.z; p.h[3] = (_Float16)v.w;
  *(unsigned long long*)(kf + ((size_t)(b * NKV + hkv) * NS + kv) * ND + d4) = p.u;
}

// ---------------- pre-pass B: V f32 -> f16 transposed, -> [b][hkv][d][kv] ----------------
__global__ __launch_bounds__(256)
void cvt_vt(const float* __restrict__ vg, _Float16* __restrict__ vt)
{
  __shared__ _Float16 T[ND][KT];                // 16 KB transpose tile
  const int tid = threadIdx.x;
  const int kvt = blockIdx.x;                    // 16 kv-tiles of 64
  const int b   = blockIdx.y;
  const int hkv = blockIdx.z;

#pragma unroll
  for (int pass = 0; pass < 8; ++pass) {
    int kvr = (tid >> 5) + pass * 8;            // 0..63
    int d4  = (tid & 31) * 4;
    float4 v = ((const float4*)vg)[(size_t)(b * NS + kvt * KT + kvr) * 256 + hkv * 32 + (tid & 31)];
    T[d4 + 0][kvr] = (_Float16)v.x;
    T[d4 + 1][kvr] = (_Float16)v.y;
    T[d4 + 2][kvr] = (_Float16)v.z;
    T[d4 + 3][kvr] = (_Float16)v.w;
  }
  __syncthreads();
  _Float16* out = vt + (size_t)(b * NKV + hkv) * ND * NS + kvt * KT;
#pragma unroll
  for (int pass = 0; pass < 4; ++pass) {
    int u = tid + pass * 256;                   // 1024 chunks of 16B
    int d = u >> 3, c = u & 7;
    *(f16x8*)(out + (size_t)d * NS + c * 8) = *(const f16x8*)&T[d][c * 8];
  }
}

// ---------------- attention: no LDS, no barriers, direct L2-hot fragment loads ----------------
__global__ __launch_bounds__(256, 1)
void attn_fwd(const float* __restrict__ qg, const _Float16* __restrict__ kf,
              const _Float16* __restrict__ vt, float* __restrict__ og)
{
  const int tid  = threadIdx.x;
  const int lane = tid & 63;
  const int w    = tid >> 6;
  const int lq   = lane & 31;
  const int hi   = lane >> 5;

  const int qtile = blockIdx.x;   // 0..7
  const int b     = blockIdx.y;
  const int h     = blockIdx.z;
  const int hkv   = h >> 2;

  const int qr0w = qtile * QT + w * 32;
  const int qrow = qr0w + lq;

  const float QS = 0.08838834764831845f * 1.4426950408889634f;  // scale * log2(e)

  // ---- Q fragments (B-frag: col=q=lane&31, k = 8*hi + i per 16-d block) ----
  f16x8 qf[8];
  {
    const float* qp = qg + (size_t)(b * NS + qrow) * (NH * ND) + h * ND + hi * 8;
#pragma unroll
    for (int dblk = 0; dblk < 8; ++dblk) {
      float4 f0 = *(const float4*)(qp + dblk * 16);
      float4 f1 = *(const float4*)(qp + dblk * 16 + 4);
      f16x8 a;
      a[0] = (_Float16)(f0.x * QS); a[1] = (_Float16)(f0.y * QS);
      a[2] = (_Float16)(f0.z * QS); a[3] = (_Float16)(f0.w * QS);
      a[4] = (_Float16)(f1.x * QS); a[5] = (_Float16)(f1.y * QS);
      a[6] = (_Float16)(f1.z * QS); a[7] = (_Float16)(f1.w * QS);
      qf[dblk] = a;
    }
  }

  f32x16 acc[4];
#pragma unroll
  for (int nb = 0; nb < 4; ++nb)
#pragma unroll
    for (int r = 0; r < 16; ++r) acc[nb][r] = 0.f;
  float m_run = -1e30f, l_run = 0.f;

  const _Float16* kbase = kf + (size_t)(b * NKV + hkv) * NS * ND;
  const _Float16* vbase = vt + (size_t)(b * NKV + hkv) * ND * NS;

  const int nt = qr0w / KT + 1;      // per-wave causal trip count
  for (int ti = 0; ti < nt; ++ti) {
    const int kv0 = ti * KT;

    // ---- swapped QK^T: P^T[kv][q], K A-frags direct from global (L1/L2-hot) ----
    f32x16 s[2];
#pragma unroll
    for (int r = 0; r < 16; ++r) { s[0][r] = 0.f; s[1][r] = 0.f; }
    const _Float16* kr0 = kbase + (size_t)(kv0 + lq) * ND + hi * 8;
    const _Float16* kr1 = kbase + (size_t)(kv0 + 32 + lq) * ND + hi * 8;
    __builtin_amdgcn_s_setprio(1);
#pragma unroll
    for (int dblk = 0; dblk < 8; ++dblk) {
      f16x8 k0 = *(const f16x8*)(kr0 + dblk * 16);
      f16x8 k1 = *(const f16x8*)(kr1 + dblk * 16);
      s[0] = __builtin_amdgcn_mfma_f32_32x32x16_f16(k0, qf[dblk], s[0], 0, 0, 0);
      s[1] = __builtin_amdgcn_mfma_f32_32x32x16_f16(k1, qf[dblk], s[1], 0, 0, 0);
    }
    __builtin_amdgcn_s_setprio(0);

    // ---- causal mask (diagonal tiles only) ----
    if (kv0 + KT - 1 > qr0w) {
      const int thr = qrow - kv0;
#pragma unroll
      for (int kb = 0; kb < 2; ++kb)
#pragma unroll
        for (int r = 0; r < 16; ++r) {
          int kvl = kb * 32 + (r & 3) + 8 * (r >> 2) + 4 * hi;
          if (kvl > thr) s[kb][r] = -1e30f;
        }
    }

    // ---- online softmax with defer-max (T13, THR=8 in log2 units) ----
    float pmax = s[0][0];
#pragma unroll
    for (int r = 1; r < 16; ++r) pmax = fmaxf(pmax, s[0][r]);
#pragma unroll
    for (int r = 0; r < 16; ++r) pmax = fmaxf(pmax, s[1][r]);
    {
      u32x2 pr = swap32(pmax);
      pmax = fmaxf(asf(pr[0]), asf(pr[1]));
    }
    const int need = !__all(pmax <= m_run + 8.0f);
    if (need) {
      const float mn = fmaxf(m_run, pmax);
      const float al = exp2fast(m_run - mn);
      m_run = mn;
#pragma unroll
      for (int r = 0; r < 16; ++r) {
        int row = (r & 3) + 8 * (r >> 2) + 4 * hi;
        float a = __shfl(al, row, 64);
#pragma unroll
        for (int nb = 0; nb < 4; ++nb) acc[nb][r] *= a;
      }
      l_run *= al;
    }
    float rs = 0.f;
#pragma unroll
    for (int kb = 0; kb < 2; ++kb)
#pragma unroll
      for (int r = 0; r < 16; ++r) {
        float p = exp2fast(s[kb][r] - m_run);
        s[kb][r] = p;
        rs += p;
      }
    {
      u32x2 sr = swap32(rs);
      rs = asf(sr[0]) + asf(sr[1]);
    }
    l_run += rs;

    // ---- P -> A-fragments in-register (cvt_pk + permlane32_swap) ----
    f16x8 pa[4];
#pragma unroll
    for (int t = 0; t < 4; ++t) {
      const int kb = t >> 1, rb = (t & 1) * 8;
      unsigned w0 = pkrtz_u(s[kb][rb + 0], s[kb][rb + 1]);
      unsigned w1 = pkrtz_u(s[kb][rb + 2], s[kb][rb + 3]);
      unsigned w2 = pkrtz_u(s[kb][rb + 4], s[kb][rb + 5]);
      unsigned w3 = pkrtz_u(s[kb][rb + 6], s[kb][rb + 7]);
      u32x2 p02 = __builtin_amdgcn_permlane32_swap(w0, w2, false, false);
      u32x2 p13 = __builtin_amdgcn_permlane32_swap(w1, w3, false, false);
      union { unsigned u[4]; f16x8 v; } pw;
      pw.u[0] = p02[0]; pw.u[1] = p13[0]; pw.u[2] = p02[1]; pw.u[3] = p13[1];
      pa[t] = pw.v;
    }

    // ---- O += P V : V^T B-frags direct from global (L1/L2-hot) ----
    const _Float16* vr = vbase + (size_t)lq * NS + kv0 + hi * 8;
    __builtin_amdgcn_s_setprio(1);
#pragma unroll
    for (int t = 0; t < 4; ++t) {
#pragma unroll
      for (int nb = 0; nb < 4; ++nb) {
        f16x8 vbF = *(const f16x8*)(vr + (size_t)(nb * 32) * NS + t * 16);
        acc[nb] = __builtin_amdgcn_mfma_f32_32x32x16_f16(pa[t], vbF, acc[nb], 0, 0, 0);
      }
    }
    __builtin_amdgcn_s_setprio(0);
  }

  // ---- epilogue: divide by l, coalesced f32 stores ----
  const float linv = 1.0f / l_run;
#pragma unroll
  for (int r = 0; r < 16; ++r) {
    int row = (r & 3) + 8 * (r >> 2) + 4 * hi;
    float li = __shfl(linv, row, 64);
    float* op = og + (size_t)(b * NS + qr0w + row) * (NH * ND) + h * ND + lq;
#pragma unroll
    for (int nb = 0; nb < 4; ++nb)
      op[nb * 32] = acc[nb][r] * li;
  }
}

extern "C" void kernel_launch(void* const* d_in, const int* in_sizes, int n_in,
                              void* d_out, int out_size, void* d_ws, size_t ws_size,
                              hipStream_t stream) {
  const float* q = (const float*)d_in[0];
  const float* k = (const float*)d_in[1];
  const float* v = (const float*)d_in[2];
  float* o = (float*)d_out;

  const size_t KSZ = (size_t)NB * NKV * NS * ND * sizeof(_Float16);  // 16.78 MB
  if (ws_size < 2 * KSZ) return;     // fail loudly (output stays poisoned)
  _Float16* kf = (_Float16*)d_ws;
  _Float16* vt = (_Float16*)((char*)d_ws + KSZ);

  cvt_k<<<dim3((NB * NS * 256) / 256), 256, 0, stream>>>(k, kf);
  cvt_vt<<<dim3(NS / KT, NB, NKV), 256, 0, stream>>>(v, vt);
  attn_fwd<<<dim3(NS / QT, NB, NH), 256, 0, stream>>>(q, kf, vt, o);
}

// Round 10
// 334.961 us; speedup vs baseline: 1.8225x; 1.8225x over previous
//
#include <hip/hip_runtime.h>

#define NB 8
#define NS 1024
#define NH 32
#define NKV 8
#define ND 128
#define QT 128     // per block: 4 waves x 32 q-rows -> 2 independent blocks/CU
#define KT 64

typedef _Float16 f16x8 __attribute__((ext_vector_type(8)));
typedef _Float16 f16x4 __attribute__((ext_vector_type(4)));
typedef _Float16 f16x2 __attribute__((ext_vector_type(2)));
typedef __fp16 fp16x2 __attribute__((ext_vector_type(2)));
typedef float f32x16 __attribute__((ext_vector_type(16)));
typedef unsigned int u32x2 __attribute__((ext_vector_type(2)));

__device__ __forceinline__ float exp2fast(float x) { return __builtin_amdgcn_exp2f(x); }

__device__ __forceinline__ unsigned pkrtz_u(float a, float b) {
  union { fp16x2 h; unsigned u; } c;
  c.h = __builtin_amdgcn_cvt_pkrtz(a, b);
  return c.u;
}
__device__ __forceinline__ u32x2 swap32(float x) {
  union { float f; unsigned u; } c; c.f = x;
  return __builtin_amdgcn_permlane32_swap(c.u, c.u, false, false);
}
__device__ __forceinline__ float asf(unsigned u) { union { unsigned u; float f; } c; c.u = u; return c.f; }
// 3-bit chunk swizzle for 128B V^T rows
__device__ __forceinline__ int gsw3(int d) { return ((d ^ (d >> 3)) & 7) << 4; }

__global__ __launch_bounds__(256, 1)   // natural alloc (~140 VGPR). (256,3)/(512,4) coerce the allocator -> spills (R6/R8)
void attn_fwd(const float* __restrict__ qg, const float* __restrict__ kg,
              const float* __restrict__ vg, float* __restrict__ og)
{
  // single-buffered: K 16KB (64 rows x 256B, byte ^= (kv&15)<<4),
  //                  V^T 16KB (128 d-rows x 128B, chunk ^= gsw3(d))   -> 32KB total
  __shared__ __align__(16) _Float16 Klds[KT * 128];
  __shared__ __align__(16) _Float16 VTlds[128 * 64];

  const int tid  = threadIdx.x;
  const int lane = tid & 63;
  const int w    = tid >> 6;
  const int lq   = lane & 31;
  const int hi   = lane >> 5;

  const int qtile = blockIdx.x;   // 0..7
  const int b     = blockIdx.y;
  const int h     = blockIdx.z;
  const int hkv   = h >> 2;

  const int qr0w = qtile * QT + w * 32;
  const int qrow = qr0w + lq;

  const float QS = 0.08838834764831845f * 1.4426950408889634f;  // scale * log2(e)

  // ---- Q fragments (B-frag: col=q=lane&31, k = 8*hi + i per 16-d block) ----
  f16x8 qf[8];
  {
    const float* qp = qg + (size_t)(b * NS + qrow) * (NH * ND) + h * ND + hi * 8;
#pragma unroll
    for (int dblk = 0; dblk < 8; ++dblk) {
      float4 f0 = *(const float4*)(qp + dblk * 16);
      float4 f1 = *(const float4*)(qp + dblk * 16 + 4);
      f16x8 a;
      a[0] = (_Float16)(f0.x * QS); a[1] = (_Float16)(f0.y * QS);
      a[2] = (_Float16)(f0.z * QS); a[3] = (_Float16)(f0.w * QS);
      a[4] = (_Float16)(f1.x * QS); a[5] = (_Float16)(f1.y * QS);
      a[6] = (_Float16)(f1.z * QS); a[7] = (_Float16)(f1.w * QS);
      qf[dblk] = a;
    }
  }

  f32x16 acc[4];
#pragma unroll
  for (int nb = 0; nb < 4; ++nb)
#pragma unroll
    for (int r = 0; r < 16; ++r) acc[nb][r] = 0.f;
  float m_run = -1e30f, l_run = 0.f;

  const float* kbase0 = kg + (size_t)(b * NS) * (NKV * ND) + hkv * ND;
  const float* vbase0 = vg + (size_t)(b * NS) * (NKV * ND) + hkv * ND;

  const int d4_s = (tid & 31) * 4;

  const int nt = 2 * (qtile + 1);
  for (int ti = 0; ti < nt; ++ti) {
    const int kv0 = ti * KT;

    // ---- stage K tile (64x128 f32 -> f16, swizzled): 8 rows per pass ----
    {
      const float* kb_ = kbase0 + (size_t)kv0 * (NKV * ND);
#pragma unroll
      for (int it = 0; it < 8; ++it) {
        int f   = tid + it * 256;
        int kvr = f >> 5;
        float4 kk = *(const float4*)(kb_ + (size_t)kvr * (NKV * ND) + d4_s);
        union { f16x4 h; unsigned long long u; } pk;
        pk.h[0] = (_Float16)kk.x; pk.h[1] = (_Float16)kk.y;
        pk.h[2] = (_Float16)kk.z; pk.h[3] = (_Float16)kk.w;
        *(unsigned long long*)((char*)Klds + kvr * 256 + ((d4_s * 2) ^ ((kvr & 15) << 4))) = pk.u;
      }
    }
    // ---- stage V^T (kv-quad transpose -> b64 writes, swizzled): 32 rows per pass ----
    {
      const float* vb_ = vbase0 + (size_t)kv0 * (NKV * ND);
#pragma unroll
      for (int it = 0; it < 2; ++it) {
        int kvq = (tid >> 5) + it * 8;       // kv quad 0..15
        float4 v0 = *(const float4*)(vb_ + (size_t)(4 * kvq + 0) * (NKV * ND) + d4_s);
        float4 v1 = *(const float4*)(vb_ + (size_t)(4 * kvq + 1) * (NKV * ND) + d4_s);
        float4 v2 = *(const float4*)(vb_ + (size_t)(4 * kvq + 2) * (NKV * ND) + d4_s);
        float4 v3 = *(const float4*)(vb_ + (size_t)(4 * kvq + 3) * (NKV * ND) + d4_s);
        float e0[4] = {v0.x, v0.y, v0.z, v0.w};
        float e1[4] = {v1.x, v1.y, v1.z, v1.w};
        float e2[4] = {v2.x, v2.y, v2.z, v2.w};
        float e3[4] = {v3.x, v3.y, v3.z, v3.w};
#pragma unroll
        for (int i = 0; i < 4; ++i) {
          int d = d4_s + i;
          union { f16x4 h; unsigned long long u; } pv;
          pv.h[0] = (_Float16)e0[i]; pv.h[1] = (_Float16)e1[i];
          pv.h[2] = (_Float16)e2[i]; pv.h[3] = (_Float16)e3[i];
          *(unsigned long long*)((char*)VTlds + d * 128 + ((kvq * 8) ^ gsw3(d))) = pv.u;
        }
      }
    }
    __syncthreads();

    if (kv0 <= qr0w + 31) {          // wave-uniform causal tile skip
      // ---- swapped QK^T: P^T[kv][q] ----
      f32x16 s[2];
#pragma unroll
      for (int r = 0; r < 16; ++r) { s[0][r] = 0.f; s[1][r] = 0.f; }
      __builtin_amdgcn_s_setprio(1);
#pragma unroll
      for (int dblk = 0; dblk < 8; ++dblk) {
        int soff = (dblk * 32 + 16 * hi) ^ ((lq & 15) << 4);
        f16x8 k0 = *(const f16x8*)((const char*)Klds + lq * 256 + soff);
        f16x8 k1 = *(const f16x8*)((const char*)Klds + (lq + 32) * 256 + soff);
        s[0] = __builtin_amdgcn_mfma_f32_32x32x16_f16(k0, qf[dblk], s[0], 0, 0, 0);
        s[1] = __builtin_amdgcn_mfma_f32_32x32x16_f16(k1, qf[dblk], s[1], 0, 0, 0);
      }
      __builtin_amdgcn_s_setprio(0);

      // ---- causal mask (diagonal tiles only) ----
      if (kv0 + KT - 1 > qr0w) {
        const int thr = qrow - kv0;
#pragma unroll
        for (int kb = 0; kb < 2; ++kb)
#pragma unroll
          for (int r = 0; r < 16; ++r) {
            int kvl = kb * 32 + (r & 3) + 8 * (r >> 2) + 4 * hi;
            if (kvl > thr) s[kb][r] = -1e30f;
          }
      }

      // ---- online softmax with defer-max (T13, THR=8 in log2 units) ----
      float pmax = s[0][0];
#pragma unroll
      for (int r = 1; r < 16; ++r) pmax = fmaxf(pmax, s[0][r]);
#pragma unroll
      for (int r = 0; r < 16; ++r) pmax = fmaxf(pmax, s[1][r]);
      {
        u32x2 pr = swap32(pmax);
        pmax = fmaxf(asf(pr[0]), asf(pr[1]));
      }
      const int need = !__all(pmax <= m_run + 8.0f);
      if (need) {
        const float mn = fmaxf(m_run, pmax);
        const float al = exp2fast(m_run - mn);
        m_run = mn;
#pragma unroll
        for (int r = 0; r < 16; ++r) {
          int row = (r & 3) + 8 * (r >> 2) + 4 * hi;
          float a = __shfl(al, row, 64);
#pragma unroll
          for (int nb = 0; nb < 4; ++nb) acc[nb][r] *= a;
        }
        l_run *= al;
      }
      float rs = 0.f;
#pragma unroll
      for (int kb = 0; kb < 2; ++kb)
#pragma unroll
        for (int r = 0; r < 16; ++r) {
          float p = exp2fast(s[kb][r] - m_run);
          s[kb][r] = p;
          rs += p;
        }
      {
        u32x2 sr = swap32(rs);
        rs = asf(sr[0]) + asf(sr[1]);
      }
      l_run += rs;

      // ---- P -> A-fragments in-register (cvt_pk + permlane32_swap) ----
      f16x8 pa[4];
#pragma unroll
      for (int t = 0; t < 4; ++t) {
        const int kb = t >> 1, rb = (t & 1) * 8;
        unsigned w0 = pkrtz_u(s[kb][rb + 0], s[kb][rb + 1]);
        unsigned w1 = pkrtz_u(s[kb][rb + 2], s[kb][rb + 3]);
        unsigned w2 = pkrtz_u(s[kb][rb + 4], s[kb][rb + 5]);
        unsigned w3 = pkrtz_u(s[kb][rb + 6], s[kb][rb + 7]);
        u32x2 p02 = __builtin_amdgcn_permlane32_swap(w0, w2, false, false);
        u32x2 p13 = __builtin_amdgcn_permlane32_swap(w1, w3, false, false);
        union { unsigned u[4]; f16x8 v; } pw;
        pw.u[0] = p02[0]; pw.u[1] = p13[0]; pw.u[2] = p02[1]; pw.u[3] = p13[1];
        pa[t] = pw.v;
      }

      // ---- O += P V ----
      __builtin_amdgcn_s_setprio(1);
#pragma unroll
      for (int t = 0; t < 4; ++t) {
        int koff = t * 32 + 16 * hi;
#pragma unroll
        for (int nb = 0; nb < 4; ++nb) {
          int d = nb * 32 + lq;
          f16x8 vb = *(const f16x8*)((const char*)VTlds + d * 128 + (koff ^ gsw3(d)));
          acc[nb] = __builtin_amdgcn_mfma_f32_32x32x16_f16(pa[t], vb, acc[nb], 0, 0, 0);
        }
      }
      __builtin_amdgcn_s_setprio(0);
    }
    __syncthreads();                  // protect buffer before next stage
  }

  // ---- epilogue: divide by l, coalesced f32 stores ----
  const float linv = 1.0f / l_run;
#pragma unroll
  for (int r = 0; r < 16; ++r) {
    int row = (r & 3) + 8 * (r >> 2) + 4 * hi;
    float li = __shfl(linv, row, 64);
    float* op = og + (size_t)(b * NS + qr0w + row) * (NH * ND) + h * ND + lq;
#pragma unroll
    for (int nb = 0; nb < 4; ++nb)
      op[nb * 32] = acc[nb][r] * li;
  }
}

extern "C" void kernel_launch(void* const* d_in, const int* in_sizes, int n_in,
                              void* d_out, int out_size, void* d_ws, size_t ws_size,
                              hipStream_t stream) {
  const float* q = (const float*)d_in[0];
  const float* k = (const float*)d_in[1];
  const float* v = (const float*)d_in[2];
  float* o = (float*)d_out;
  dim3 grid(NS / QT, NB, NH);
  attn_fwd<<<grid, 256, 0, stream>>>(q, k, v, o);
}

// Round 11
// 217.665 us; speedup vs baseline: 2.8047x; 1.5389x over previous
//
#include <hip/hip_runtime.h>

#define NB 8
#define NS 1024
#define NH 32
#define NKV 8
#define ND 128
#define QT 256     // attn: 8 waves x 32 q-rows
#define KT 64

typedef _Float16 f16x8 __attribute__((ext_vector_type(8)));
typedef _Float16 f16x4 __attribute__((ext_vector_type(4)));
typedef __fp16 fp16x2 __attribute__((ext_vector_type(2)));
typedef float f32x16 __attribute__((ext_vector_type(16)));
typedef unsigned int u32x2 __attribute__((ext_vector_type(2)));

__device__ __forceinline__ float exp2fast(float x) { return __builtin_amdgcn_exp2f(x); }
__device__ __forceinline__ unsigned pkrtz_u(float a, float b) {
  union { fp16x2 h; unsigned u; } c;
  c.h = __builtin_amdgcn_cvt_pkrtz(a, b);
  return c.u;
}
__device__ __forceinline__ u32x2 swap32(float x) {
  union { float f; unsigned u; } c; c.f = x;
  return __builtin_amdgcn_permlane32_swap(c.u, c.u, false, false);
}
__device__ __forceinline__ float asf(unsigned u) { union { unsigned u; float f; } c; c.u = u; return c.f; }
__device__ __forceinline__ int gsw3(int d) { return ((d ^ (d >> 3)) & 7) << 4; }

// async global->LDS, 16B per lane; LDS dest = wave-uniform base + lane*16
__device__ __forceinline__ void gload16(const void* g, void* l) {
  __builtin_amdgcn_global_load_lds(
      (const __attribute__((address_space(1))) unsigned int*)g,
      (__attribute__((address_space(3))) unsigned int*)l, 16, 0, 0);
}

// ---- pre-pass A: K f32 [t][dkv] -> f16 [b][hkv][kv][256B row, PRE-SWIZZLED (2d)^((kv&15)<<4)] ----
__global__ __launch_bounds__(256)
void cvt_k(const float* __restrict__ kg, char* __restrict__ wsK)
{
  int g = blockIdx.x * 256 + threadIdx.x;       // float4 index
  int t = g >> 8, c4 = g & 255;
  int b = t >> 10, kv = t & 1023;
  int hkv = c4 >> 5, d4 = (c4 & 31) * 4;
  float4 v = ((const float4*)kg)[g];
  union { f16x4 h; unsigned long long u; } p;
  p.h[0] = (_Float16)v.x; p.h[1] = (_Float16)v.y;
  p.h[2] = (_Float16)v.z; p.h[3] = (_Float16)v.w;
  size_t row = (size_t)(b * NKV + hkv) * NS + kv;
  *(unsigned long long*)(wsK + row * 256 + ((d4 * 2) ^ ((kv & 15) << 4))) = p.u;
}

// ---- pre-pass B: V f32 -> f16 V^T, tile-blocked [b][hkv][kvt][d][kv64], rows PRE-SWIZZLED gsw3 ----
__global__ __launch_bounds__(256)
void cvt_vt(const float* __restrict__ vg, _Float16* __restrict__ wsV)
{
  __shared__ _Float16 T[ND][KT];                // 16 KB transpose tile
  const int tid = threadIdx.x;
  const int kvt = blockIdx.x, b = blockIdx.y, hkv = blockIdx.z;
#pragma unroll
  for (int pass = 0; pass < 8; ++pass) {
    int kvr = (tid >> 5) + pass * 8;            // 0..63
    int d4  = (tid & 31) * 4;
    float4 v = ((const float4*)vg)[(size_t)(b * NS + kvt * KT + kvr) * 256 + hkv * 32 + (tid & 31)];
    T[d4 + 0][kvr] = (_Float16)v.x;
    T[d4 + 1][kvr] = (_Float16)v.y;
    T[d4 + 2][kvr] = (_Float16)v.z;
    T[d4 + 3][kvr] = (_Float16)v.w;
  }
  __syncthreads();
  _Float16* out = wsV + ((size_t)(b * NKV + hkv) * 16 + kvt) * 8192;   // 16KB tile block
#pragma unroll
  for (int pass = 0; pass < 4; ++pass) {
    int u = tid + pass * 256;                   // 16B chunk id
    int d = u >> 3, c = u & 7;
    int kv8 = ((c * 16) ^ gsw3(d)) >> 1;        // source kv octet for this swizzled slot
    *(f16x8*)(out + d * 64 + c * 8) = *(const f16x8*)&T[d][kv8];
  }
}

// ---- attention: dbuf LDS filled by global_load_lds from pre-swizzled ws ----
__global__ __launch_bounds__(512, 1)
void attn_fwd(const float* __restrict__ qg, const char* __restrict__ wsK,
              const char* __restrict__ wsV, float* __restrict__ og)
{
  __shared__ __align__(16) _Float16 Klds[2][KT * 128];   // 2x16KB
  __shared__ __align__(16) _Float16 Vlds[2][128 * 64];   // 2x16KB

  const int tid  = threadIdx.x;
  const int lane = tid & 63;
  const int w    = tid >> 6;
  const int lq   = lane & 31;
  const int hi   = lane >> 5;

  const int qtile = blockIdx.x;   // 0..3
  const int b     = blockIdx.y;
  const int h     = blockIdx.z;
  const int hkv   = h >> 2;
  const int bh    = b * NKV + hkv;

  const int qr0w = qtile * QT + w * 32;
  const int qrow = qr0w + lq;

  const float QS = 0.08838834764831845f * 1.4426950408889634f;  // scale * log2(e)

  // ---- Q fragments (B-frag: col=q=lane&31, k = 8*hi + i per 16-d block) ----
  f16x8 qf[8];
  {
    const float* qp = qg + (size_t)(b * NS + qrow) * (NH * ND) + h * ND + hi * 8;
#pragma unroll
    for (int dblk = 0; dblk < 8; ++dblk) {
      float4 f0 = *(const float4*)(qp + dblk * 16);
      float4 f1 = *(const float4*)(qp + dblk * 16 + 4);
      f16x8 a;
      a[0] = (_Float16)(f0.x * QS); a[1] = (_Float16)(f0.y * QS);
      a[2] = (_Float16)(f0.z * QS); a[3] = (_Float16)(f0.w * QS);
      a[4] = (_Float16)(f1.x * QS); a[5] = (_Float16)(f1.y * QS);
      a[6] = (_Float16)(f1.z * QS); a[7] = (_Float16)(f1.w * QS);
      qf[dblk] = a;
    }
  }

  f32x16 acc[4];
#pragma unroll
  for (int nb = 0; nb < 4; ++nb)
#pragma unroll
    for (int r = 0; r < 16; ++r) acc[nb][r] = 0.f;
  float m_run = -1e30f, l_run = 0.f;

  const char* wsKb = wsK + (size_t)bh * NS * 256;        // K rows base for this (b,hkv)
  const char* wsVb = wsV + (size_t)bh * 16 * 16384;      // V tile blocks base

#define STAGE(TI, BUF)                                                     \
  {                                                                        \
    const char* gk = wsKb + (size_t)(TI) * 16384;                          \
    const char* gv = wsVb + (size_t)(TI) * 16384;                          \
    char* lk = (char*)&Klds[BUF][0] + w * 1024;                            \
    char* lv = (char*)&Vlds[BUF][0] + w * 1024;                            \
    gload16(gk + w * 1024 + lane * 16, lk);                                \
    gload16(gk + 8192 + w * 1024 + lane * 16, lk + 8192);                  \
    gload16(gv + w * 1024 + lane * 16, lv);                                \
    gload16(gv + 8192 + w * 1024 + lane * 16, lv + 8192);                  \
  }

  const int nt = (qtile + 1) * (QT / KT);

  STAGE(0, 0);
  __syncthreads();                  // implicit vmcnt(0) drains the DMA

  for (int ti = 0; ti < nt; ++ti) {
    const int kv0 = ti * KT;
    const int cur = ti & 1;
    const bool hn = (ti + 1 < nt);

    if (hn) STAGE(ti + 1, cur ^ 1);   // DMA in flight under compute

    if (kv0 <= qr0w + 31) {           // wave-uniform causal tile skip
      const char* Kb = (const char*)&Klds[cur][0];
      const char* Vb = (const char*)&Vlds[cur][0];

      // ---- swapped QK^T: P^T[kv][q] ----
      f32x16 s[2];
#pragma unroll
      for (int r = 0; r < 16; ++r) { s[0][r] = 0.f; s[1][r] = 0.f; }
      __builtin_amdgcn_s_setprio(1);
#pragma unroll
      for (int dblk = 0; dblk < 8; ++dblk) {
        int soff = (dblk * 32 + 16 * hi) ^ ((lq & 15) << 4);
        f16x8 k0 = *(const f16x8*)(Kb + lq * 256 + soff);
        f16x8 k1 = *(const f16x8*)(Kb + (lq + 32) * 256 + soff);
        s[0] = __builtin_amdgcn_mfma_f32_32x32x16_f16(k0, qf[dblk], s[0], 0, 0, 0);
        s[1] = __builtin_amdgcn_mfma_f32_32x32x16_f16(k1, qf[dblk], s[1], 0, 0, 0);
      }
      __builtin_amdgcn_s_setprio(0);

      // ---- causal mask (diagonal tiles only) ----
      if (kv0 + KT - 1 > qr0w) {
        const int thr = qrow - kv0;
#pragma unroll
        for (int kb = 0; kb < 2; ++kb)
#pragma unroll
          for (int r = 0; r < 16; ++r) {
            int kvl = kb * 32 + (r & 3) + 8 * (r >> 2) + 4 * hi;
            if (kvl > thr) s[kb][r] = -1e30f;
          }
      }

      // ---- online softmax with defer-max (T13, THR=8 in log2 units) ----
      float pmax = s[0][0];
#pragma unroll
      for (int r = 1; r < 16; ++r) pmax = fmaxf(pmax, s[0][r]);
#pragma unroll
      for (int r = 0; r < 16; ++r) pmax = fmaxf(pmax, s[1][r]);
      {
        u32x2 pr = swap32(pmax);
        pmax = fmaxf(asf(pr[0]), asf(pr[1]));
      }
      const int need = !__all(pmax <= m_run + 8.0f);
      if (need) {
        const float mn = fmaxf(m_run, pmax);
        const float al = exp2fast(m_run - mn);
        m_run = mn;
#pragma unroll
        for (int r = 0; r < 16; ++r) {
          int row = (r & 3) + 8 * (r >> 2) + 4 * hi;
          float a = __shfl(al, row, 64);
#pragma unroll
          for (int nb = 0; nb < 4; ++nb) acc[nb][r] *= a;
        }
        l_run *= al;
      }
      float rs = 0.f;
#pragma unroll
      for (int kb = 0; kb < 2; ++kb)
#pragma unroll
        for (int r = 0; r < 16; ++r) {
          float p = exp2fast(s[kb][r] - m_run);
          s[kb][r] = p;
          rs += p;
        }
      {
        u32x2 sr = swap32(rs);
        rs = asf(sr[0]) + asf(sr[1]);
      }
      l_run += rs;

      // ---- P -> A-fragments in-register (cvt_pk + permlane32_swap) ----
      f16x8 pa[4];
#pragma unroll
      for (int t = 0; t < 4; ++t) {
        const int kb = t >> 1, rb = (t & 1) * 8;
        unsigned w0 = pkrtz_u(s[kb][rb + 0], s[kb][rb + 1]);
        unsigned w1 = pkrtz_u(s[kb][rb + 2], s[kb][rb + 3]);
        unsigned w2 = pkrtz_u(s[kb][rb + 4], s[kb][rb + 5]);
        unsigned w3 = pkrtz_u(s[kb][rb + 6], s[kb][rb + 7]);
        u32x2 p02 = __builtin_amdgcn_permlane32_swap(w0, w2, false, false);
        u32x2 p13 = __builtin_amdgcn_permlane32_swap(w1, w3, false, false);
        union { unsigned u[4]; f16x8 v; } pw;
        pw.u[0] = p02[0]; pw.u[1] = p13[0]; pw.u[2] = p02[1]; pw.u[3] = p13[1];
        pa[t] = pw.v;
      }

      // ---- O += P V ----
      __builtin_amdgcn_s_setprio(1);
#pragma unroll
      for (int t = 0; t < 4; ++t) {
        int koff = t * 32 + 16 * hi;
#pragma unroll
        for (int nb = 0; nb < 4; ++nb) {
          int d = nb * 32 + lq;
          f16x8 vb = *(const f16x8*)(Vb + d * 128 + (koff ^ gsw3(d)));
          acc[nb] = __builtin_amdgcn_mfma_f32_32x32x16_f16(pa[t], vb, acc[nb], 0, 0, 0);
        }
      }
      __builtin_amdgcn_s_setprio(0);
    }

    __syncthreads();                  // drains this wave's DMA (issued ~a compute-phase ago)
  }

  // ---- epilogue: divide by l, coalesced f32 stores ----
  const float linv = 1.0f / l_run;
#pragma unroll
  for (int r = 0; r < 16; ++r) {
    int row = (r & 3) + 8 * (r >> 2) + 4 * hi;
    float li = __shfl(linv, row, 64);
    float* op = og + (size_t)(b * NS + qr0w + row) * (NH * ND) + h * ND + lq;
#pragma unroll
    for (int nb = 0; nb < 4; ++nb)
      op[nb * 32] = acc[nb][r] * li;
  }
#undef STAGE
}

extern "C" void kernel_launch(void* const* d_in, const int* in_sizes, int n_in,
                              void* d_out, int out_size, void* d_ws, size_t ws_size,
                              hipStream_t stream) {
  const float* q = (const float*)d_in[0];
  const float* k = (const float*)d_in[1];
  const float* v = (const float*)d_in[2];
  float* o = (float*)d_out;

  const size_t KSZ = (size_t)NB * NKV * NS * ND * sizeof(_Float16);  // 16.78 MB each
  if (ws_size < 2 * KSZ) return;     // fail loudly (output stays poisoned)
  char*     wsK = (char*)d_ws;
  _Float16* wsV = (_Float16*)((char*)d_ws + KSZ);

  cvt_k <<<dim3((NB * NS * 256) / 256), 256, 0, stream>>>(k, wsK);
  cvt_vt<<<dim3(NS / KT, NB, NKV),      256, 0, stream>>>(v, wsV);
  attn_fwd<<<dim3(NS / QT, NB, NH),     512, 0, stream>>>(q, wsK, (const char*)wsV, o);
}

// Round 12
// 195.046 us; speedup vs baseline: 3.1299x; 1.1160x over previous
//
#include <hip/hip_runtime.h>

#define NB 8
#define NS 1024
#define NH 32
#define NKV 8
#define ND 128
#define QT 128     // attn: 4 waves x 32 q-rows per block, barrier-free
#define KT 64

typedef _Float16 f16x8 __attribute__((ext_vector_type(8)));
typedef __fp16 fp16x2 __attribute__((ext_vector_type(2)));
typedef float f32x16 __attribute__((ext_vector_type(16)));
typedef unsigned int u32x2 __attribute__((ext_vector_type(2)));

__device__ __forceinline__ float exp2fast(float x) { return __builtin_amdgcn_exp2f(x); }
__device__ __forceinline__ unsigned pkrtz_u(float a, float b) {
  union { fp16x2 h; unsigned u; } c;
  c.h = __builtin_amdgcn_cvt_pkrtz(a, b);
  return c.u;
}
__device__ __forceinline__ u32x2 swap32(float x) {
  union { float f; unsigned u; } c; c.f = x;
  return __builtin_amdgcn_permlane32_swap(c.u, c.u, false, false);
}
__device__ __forceinline__ float asf(unsigned u) { union { unsigned u; float f; } c; c.u = u; return c.f; }

// ---- pre-pass A: K f32 [t][dkv] -> fragment-ordered f16 panels ----
// wsK layout: [panel=b*8+hkv][ti(16)][chunk=kb*8+dblk (16)][lane(64)][16B]
// lane=hi*32+lq holds K[kv=ti*64+kb*32+lq][d=dblk*16+hi*8 .. +8]
__global__ __launch_bounds__(256)
void cvt_kf(const float* __restrict__ kg, char* __restrict__ wsK)
{
  int g = blockIdx.x * 256 + threadIdx.x;      // 1M threads: one 16B f16 chunk each
  int t = g >> 7, c8 = g & 127;
  int hkv = c8 >> 4, d8 = c8 & 15;
  const float* src = kg + (size_t)t * 1024 + hkv * 128 + d8 * 8;
  float4 a = *(const float4*)src;
  float4 c = *(const float4*)(src + 4);
  f16x8 h8;
  h8[0] = (_Float16)a.x; h8[1] = (_Float16)a.y; h8[2] = (_Float16)a.z; h8[3] = (_Float16)a.w;
  h8[4] = (_Float16)c.x; h8[5] = (_Float16)c.y; h8[6] = (_Float16)c.z; h8[7] = (_Float16)c.w;
  int b  = t >> 10, kv = t & 1023;
  int ti = kv >> 6, kvl = kv & 63, kb = kvl >> 5, lq = kvl & 31;
  int dblk = d8 >> 1, hi = d8 & 1;
  size_t off = (((size_t)(b * 8 + hkv) * 16 + ti) * 16 + kb * 8 + dblk) * 1024 + (hi * 32 + lq) * 16;
  *(f16x8*)(wsK + off) = h8;
}

// ---- pre-pass B: V f32 -> fragment-ordered V^T f16 panels ----
// wsV layout: [panel][ti(16)][chunk=t*4+nb (16)][lane(64)][16B]
// lane=hi*32+lq holds V^T[d=nb*32+lq][kv=ti*64+t*16+hi*8 .. +8]
__global__ __launch_bounds__(256)
void cvt_vf(const float* __restrict__ vg, _Float16* __restrict__ wsV)
{
  __shared__ _Float16 T[ND][KT];               // 16 KB transpose tile
  const int tid = threadIdx.x;
  const int kvt = blockIdx.x, b = blockIdx.y, hkv = blockIdx.z;
#pragma unroll
  for (int pass = 0; pass < 8; ++pass) {
    int kvr = (tid >> 5) + pass * 8;           // 0..63
    int d4  = (tid & 31) * 4;
    float4 v = ((const float4*)vg)[(size_t)(b * NS + kvt * KT + kvr) * 256 + hkv * 32 + (tid & 31)];
    T[d4 + 0][kvr] = (_Float16)v.x;
    T[d4 + 1][kvr] = (_Float16)v.y;
    T[d4 + 2][kvr] = (_Float16)v.z;
    T[d4 + 3][kvr] = (_Float16)v.w;
  }
  __syncthreads();
  _Float16* out = wsV + ((size_t)(b * 8 + hkv) * 16 + kvt) * 8192;
#pragma unroll
  for (int pass = 0; pass < 4; ++pass) {
    int unit = tid + pass * 256;               // 1024 (chunk,lane) 16B units
    int c = unit >> 6, lane = unit & 63;
    int d = (c & 3) * 32 + (lane & 31);
    int kv8 = (c >> 2) * 16 + (lane >> 5) * 8;
    *(f16x8*)(out + unit * 8) = *(const f16x8*)&T[d][kv8];
  }
}

// ---- attention: barrier-free, LDS-free; fragments direct from ws (L1/L2-hot) ----
__global__ __launch_bounds__(256, 1)
void attn_fwd(const float* __restrict__ qg, const char* __restrict__ wsK,
              const char* __restrict__ wsV, float* __restrict__ og)
{
  // XCD swizzle: 2048 blocks; v = panel*32+sub; id = (v%256)*8 + v/256 inverted here.
  const int id = blockIdx.x;
  const int v  = (id & 7) * 256 + (id >> 3);   // chunk c=id&7 -> xcd c (round-robin dispatch)
  const int panel = v >> 5;                     // b*8+hkv : 8 panels (4MB) per XCD
  const int sub   = v & 31;
  const int b     = panel >> 3;
  const int hkv   = panel & 7;
  const int qtile = sub >> 2;                   // 0..7
  const int h     = hkv * 4 + (sub & 3);

  const int tid  = threadIdx.x;
  const int lane = tid & 63;
  const int w    = tid >> 6;
  const int lq   = lane & 31;
  const int hi   = lane >> 5;

  const int qr0w = qtile * QT + w * 32;
  const int qrow = qr0w + lq;

  const float QS = 0.08838834764831845f * 1.4426950408889634f;  // scale * log2(e)

  // ---- Q fragments (B-frag: col=q=lane&31, k = 8*hi + i per 16-d block) ----
  f16x8 qf[8];
  {
    const float* qp = qg + (size_t)(b * NS + qrow) * (NH * ND) + h * ND + hi * 8;
#pragma unroll
    for (int dblk = 0; dblk < 8; ++dblk) {
      float4 f0 = *(const float4*)(qp + dblk * 16);
      float4 f1 = *(const float4*)(qp + dblk * 16 + 4);
      f16x8 a;
      a[0] = (_Float16)(f0.x * QS); a[1] = (_Float16)(f0.y * QS);
      a[2] = (_Float16)(f0.z * QS); a[3] = (_Float16)(f0.w * QS);
      a[4] = (_Float16)(f1.x * QS); a[5] = (_Float16)(f1.y * QS);
      a[6] = (_Float16)(f1.z * QS); a[7] = (_Float16)(f1.w * QS);
      qf[dblk] = a;
    }
  }

  f32x16 acc[4];
#pragma unroll
  for (int nb = 0; nb < 4; ++nb)
#pragma unroll
    for (int r = 0; r < 16; ++r) acc[nb][r] = 0.f;
  float m_run = -1e30f, l_run = 0.f;

  const char* wsKb = wsK + (size_t)panel * 16 * 16384;
  const char* wsVb = wsV + (size_t)panel * 16 * 16384;

  const int nt = qr0w / KT + 1;     // per-wave causal trip count; no lockstep
  for (int ti = 0; ti < nt; ++ti) {
    const char* kt  = wsKb + (size_t)ti * 16384;
    const char* vt_ = wsVb + (size_t)ti * 16384;

    // ---- K fragments: 16 coalesced dwordx4 loads ----
    f16x8 kf[16];
#pragma unroll
    for (int c = 0; c < 16; ++c)
      kf[c] = *(const f16x8*)(kt + c * 1024 + lane * 16);

    // ---- swapped QK^T: P^T[kv][q] ----
    f32x16 s[2];
#pragma unroll
    for (int r = 0; r < 16; ++r) { s[0][r] = 0.f; s[1][r] = 0.f; }
    __builtin_amdgcn_s_setprio(1);
#pragma unroll
    for (int dblk = 0; dblk < 8; ++dblk) {
      s[0] = __builtin_amdgcn_mfma_f32_32x32x16_f16(kf[dblk],     qf[dblk], s[0], 0, 0, 0);
      s[1] = __builtin_amdgcn_mfma_f32_32x32x16_f16(kf[8 + dblk], qf[dblk], s[1], 0, 0, 0);
    }
    __builtin_amdgcn_s_setprio(0);

    // ---- V fragments issued now: latency hides under softmax ----
    f16x8 vf[16];
#pragma unroll
    for (int c = 0; c < 16; ++c)
      vf[c] = *(const f16x8*)(vt_ + c * 1024 + lane * 16);

    // ---- causal mask (final tile only) ----
    if (ti == nt - 1) {
      const int thr = qrow - ti * KT;
#pragma unroll
      for (int kb = 0; kb < 2; ++kb)
#pragma unroll
        for (int r = 0; r < 16; ++r) {
          int kvl = kb * 32 + (r & 3) + 8 * (r >> 2) + 4 * hi;
          if (kvl > thr) s[kb][r] = -1e30f;
        }
    }

    // ---- online softmax with defer-max (T13, THR=8 in log2 units) ----
    float pmax = s[0][0];
#pragma unroll
    for (int r = 1; r < 16; ++r) pmax = fmaxf(pmax, s[0][r]);
#pragma unroll
    for (int r = 0; r < 16; ++r) pmax = fmaxf(pmax, s[1][r]);
    {
      u32x2 pr = swap32(pmax);
      pmax = fmaxf(asf(pr[0]), asf(pr[1]));
    }
    const int need = !__all(pmax <= m_run + 8.0f);
    if (need) {
      const float mn = fmaxf(m_run, pmax);
      const float al = exp2fast(m_run - mn);
      m_run = mn;
#pragma unroll
      for (int r = 0; r < 16; ++r) {
        int row = (r & 3) + 8 * (r >> 2) + 4 * hi;
        float a = __shfl(al, row, 64);
#pragma unroll
        for (int nb = 0; nb < 4; ++nb) acc[nb][r] *= a;
      }
      l_run *= al;
    }
    float rs = 0.f;
#pragma unroll
    for (int kb = 0; kb < 2; ++kb)
#pragma unroll
      for (int r = 0; r < 16; ++r) {
        float p = exp2fast(s[kb][r] - m_run);
        s[kb][r] = p;
        rs += p;
      }
    {
      u32x2 sr = swap32(rs);
      rs = asf(sr[0]) + asf(sr[1]);
    }
    l_run += rs;

    // ---- P -> A-fragments in-register (cvt_pk + permlane32_swap) ----
    f16x8 pa[4];
#pragma unroll
    for (int t = 0; t < 4; ++t) {
      const int kb = t >> 1, rb = (t & 1) * 8;
      unsigned w0 = pkrtz_u(s[kb][rb + 0], s[kb][rb + 1]);
      unsigned w1 = pkrtz_u(s[kb][rb + 2], s[kb][rb + 3]);
      unsigned w2 = pkrtz_u(s[kb][rb + 4], s[kb][rb + 5]);
      unsigned w3 = pkrtz_u(s[kb][rb + 6], s[kb][rb + 7]);
      u32x2 p02 = __builtin_amdgcn_permlane32_swap(w0, w2, false, false);
      u32x2 p13 = __builtin_amdgcn_permlane32_swap(w1, w3, false, false);
      union { unsigned u[4]; f16x8 v; } pw;
      pw.u[0] = p02[0]; pw.u[1] = p13[0]; pw.u[2] = p02[1]; pw.u[3] = p13[1];
      pa[t] = pw.v;
    }

    // ---- O += P V ----
    __builtin_amdgcn_s_setprio(1);
#pragma unroll
    for (int t = 0; t < 4; ++t)
#pragma unroll
      for (int nb = 0; nb < 4; ++nb)
        acc[nb] = __builtin_amdgcn_mfma_f32_32x32x16_f16(pa[t], vf[t * 4 + nb], acc[nb], 0, 0, 0);
    __builtin_amdgcn_s_setprio(0);
  }

  // ---- epilogue: divide by l, coalesced f32 stores ----
  const float linv = 1.0f / l_run;
#pragma unroll
  for (int r = 0; r < 16; ++r) {
    int row = (r & 3) + 8 * (r >> 2) + 4 * hi;
    float li = __shfl(linv, row, 64);
    float* op = og + (size_t)(b * NS + qr0w + row) * (NH * ND) + h * ND + lq;
#pragma unroll
    for (int nb = 0; nb < 4; ++nb)
      op[nb * 32] = acc[nb][r] * li;
  }
}

extern "C" void kernel_launch(void* const* d_in, const int* in_sizes, int n_in,
                              void* d_out, int out_size, void* d_ws, size_t ws_size,
                              hipStream_t stream) {
  const float* q = (const float*)d_in[0];
  const float* k = (const float*)d_in[1];
  const float* v = (const float*)d_in[2];
  float* o = (float*)d_out;

  const size_t KSZ = (size_t)NB * NKV * NS * ND * sizeof(_Float16);  // 16.78 MB each
  if (ws_size < 2 * KSZ) return;     // fail loudly (output stays poisoned)
  char*     wsK = (char*)d_ws;
  _Float16* wsV = (_Float16*)((char*)d_ws + KSZ);

  cvt_kf<<<dim3((NB * NS * 128) / 256), 256, 0, stream>>>(k, wsK);
  cvt_vf<<<dim3(NS / KT, NB, NKV),      256, 0, stream>>>(v, wsV);
  attn_fwd<<<dim3(2048),                256, 0, stream>>>(q, wsK, (const char*)wsV, o);
}

// Round 13
// 186.951 us; speedup vs baseline: 3.2655x; 1.0433x over previous
//
#include <hip/hip_runtime.h>

#define NB 8
#define NS 1024
#define NH 32
#define NKV 8
#define ND 128
#define QT 128     // attn: 4 waves x 32 q-rows per block-phase, barrier-free
#define KT 64

typedef _Float16 f16x8 __attribute__((ext_vector_type(8)));
typedef __fp16 fp16x2 __attribute__((ext_vector_type(2)));
typedef float f32x16 __attribute__((ext_vector_type(16)));
typedef unsigned int u32x2 __attribute__((ext_vector_type(2)));

__device__ __forceinline__ float exp2fast(float x) { return __builtin_amdgcn_exp2f(x); }
__device__ __forceinline__ unsigned pkrtz_u(float a, float b) {
  union { fp16x2 h; unsigned u; } c;
  c.h = __builtin_amdgcn_cvt_pkrtz(a, b);
  return c.u;
}
__device__ __forceinline__ u32x2 swap32(float x) {
  union { float f; unsigned u; } c; c.f = x;
  return __builtin_amdgcn_permlane32_swap(c.u, c.u, false, false);
}
__device__ __forceinline__ float asf(unsigned u) { union { unsigned u; float f; } c; c.u = u; return c.f; }

// ---- pre-pass A: K f32 [t][dkv] -> fragment-ordered f16 panels ----
// wsK layout: [panel=b*8+hkv][ti(16)][chunk=kb*8+dblk (16)][lane(64)][16B]
// lane=hi*32+lq holds K[kv=ti*64+kb*32+lq][d=dblk*16+hi*8 .. +8]
__global__ __launch_bounds__(256)
void cvt_kf(const float* __restrict__ kg, char* __restrict__ wsK)
{
  int g = blockIdx.x * 256 + threadIdx.x;      // one 16B f16 chunk each
  int t = g >> 7, c8 = g & 127;
  int hkv = c8 >> 4, d8 = c8 & 15;
  const float* src = kg + (size_t)t * 1024 + hkv * 128 + d8 * 8;
  float4 a = *(const float4*)src;
  float4 c = *(const float4*)(src + 4);
  f16x8 h8;
  h8[0] = (_Float16)a.x; h8[1] = (_Float16)a.y; h8[2] = (_Float16)a.z; h8[3] = (_Float16)a.w;
  h8[4] = (_Float16)c.x; h8[5] = (_Float16)c.y; h8[6] = (_Float16)c.z; h8[7] = (_Float16)c.w;
  int b  = t >> 10, kv = t & 1023;
  int ti = kv >> 6, kvl = kv & 63, kb = kvl >> 5, lq = kvl & 31;
  int dblk = d8 >> 1, hi = d8 & 1;
  size_t off = (((size_t)(b * 8 + hkv) * 16 + ti) * 16 + kb * 8 + dblk) * 1024 + (hi * 32 + lq) * 16;
  *(f16x8*)(wsK + off) = h8;
}

// ---- pre-pass B: V f32 -> fragment-ordered V^T f16 panels ----
// wsV layout: [panel][ti(16)][chunk=t*4+nb (16)][lane(64)][16B]
// lane=hi*32+lq holds V^T[d=nb*32+lq][kv=ti*64+t*16+hi*8 .. +8]
__global__ __launch_bounds__(256)
void cvt_vf(const float* __restrict__ vg, _Float16* __restrict__ wsV)
{
  __shared__ _Float16 T[ND][KT];               // 16 KB transpose tile
  const int tid = threadIdx.x;
  const int kvt = blockIdx.x, b = blockIdx.y, hkv = blockIdx.z;
#pragma unroll
  for (int pass = 0; pass < 8; ++pass) {
    int kvr = (tid >> 5) + pass * 8;           // 0..63
    int d4  = (tid & 31) * 4;
    float4 v = ((const float4*)vg)[(size_t)(b * NS + kvt * KT + kvr) * 256 + hkv * 32 + (tid & 31)];
    T[d4 + 0][kvr] = (_Float16)v.x;
    T[d4 + 1][kvr] = (_Float16)v.y;
    T[d4 + 2][kvr] = (_Float16)v.z;
    T[d4 + 3][kvr] = (_Float16)v.w;
  }
  __syncthreads();
  _Float16* out = wsV + ((size_t)(b * 8 + hkv) * 16 + kvt) * 8192;
#pragma unroll
  for (int pass = 0; pass < 4; ++pass) {
    int unit = tid + pass * 256;               // (chunk,lane) 16B units
    int c = unit >> 6, lane = unit & 63;
    int d = (c & 3) * 32 + (lane & 31);
    int kv8 = (c >> 2) * 16 + (lane >> 5) * 8;
    *(f16x8*)(out + unit * 8) = *(const f16x8*)&T[d][kv8];
  }
}

// ---- attention: barrier-free, LDS-free; paired q-tiles for uniform block duration ----
__global__ __launch_bounds__(256, 1)
void attn_fwd(const float* __restrict__ qg, const char* __restrict__ wsK,
              const char* __restrict__ wsV, float* __restrict__ og)
{
  // 1024 blocks; XCD swizzle: xcd=id&7 gets contiguous v-range -> 8 panels (4MB) per XCD L2
  const int id = blockIdx.x;
  const int v  = (id & 7) * 128 + (id >> 3);
  const int panel = v >> 4;                     // b*8+hkv
  const int sub   = v & 15;
  const int b     = panel >> 3;
  const int hkv   = panel & 7;
  const int h     = hkv * 4 + (sub & 3);
  const int qpair = sub >> 2;                   // 0..3

  const int tid  = threadIdx.x;
  const int lane = tid & 63;
  const int w    = tid >> 6;
  const int lq   = lane & 31;
  const int hi   = lane >> 5;

  const float QS = 0.08838834764831845f * 1.4426950408889634f;  // scale * log2(e)

  const char* wsKb = wsK + (size_t)panel * 16 * 16384;
  const char* wsVb = wsV + (size_t)panel * 16 * 16384;

#pragma unroll 1
  for (int ph = 0; ph < 2; ++ph) {
    const int qtile = ph ? (7 - qpair) : qpair;   // short phase then long phase (uniform total)
    const int qr0w = qtile * QT + w * 32;
    const int qrow = qr0w + lq;

    // ---- Q fragments (B-frag: col=q=lane&31, k = 8*hi + i per 16-d block) ----
    f16x8 qf[8];
    {
      const float* qp = qg + (size_t)(b * NS + qrow) * (NH * ND) + h * ND + hi * 8;
#pragma unroll
      for (int dblk = 0; dblk < 8; ++dblk) {
        float4 f0 = *(const float4*)(qp + dblk * 16);
        float4 f1 = *(const float4*)(qp + dblk * 16 + 4);
        f16x8 a;
        a[0] = (_Float16)(f0.x * QS); a[1] = (_Float16)(f0.y * QS);
        a[2] = (_Float16)(f0.z * QS); a[3] = (_Float16)(f0.w * QS);
        a[4] = (_Float16)(f1.x * QS); a[5] = (_Float16)(f1.y * QS);
        a[6] = (_Float16)(f1.z * QS); a[7] = (_Float16)(f1.w * QS);
        qf[dblk] = a;
      }
    }

    f32x16 acc[4];
#pragma unroll
    for (int nb = 0; nb < 4; ++nb)
#pragma unroll
      for (int r = 0; r < 16; ++r) acc[nb][r] = 0.f;
    float m_run = -1e30f, l_run = 0.f;

    const int nt = qr0w / KT + 1;     // per-wave causal trip count; no lockstep
    for (int ti = 0; ti < nt; ++ti) {
      const char* kt  = wsKb + (size_t)ti * 16384;
      const char* vt_ = wsVb + (size_t)ti * 16384;

      // ---- K fragments: 16 coalesced dwordx4 loads ----
      f16x8 kf[16];
#pragma unroll
      for (int c = 0; c < 16; ++c)
        kf[c] = *(const f16x8*)(kt + c * 1024 + lane * 16);

      // ---- swapped QK^T: P^T[kv][q] ----
      f32x16 s[2];
#pragma unroll
      for (int r = 0; r < 16; ++r) { s[0][r] = 0.f; s[1][r] = 0.f; }
      __builtin_amdgcn_s_setprio(1);
#pragma unroll
      for (int dblk = 0; dblk < 8; ++dblk) {
        s[0] = __builtin_amdgcn_mfma_f32_32x32x16_f16(kf[dblk],     qf[dblk], s[0], 0, 0, 0);
        s[1] = __builtin_amdgcn_mfma_f32_32x32x16_f16(kf[8 + dblk], qf[dblk], s[1], 0, 0, 0);
      }
      __builtin_amdgcn_s_setprio(0);

      // ---- V fragments issued now: latency hides under softmax ----
      f16x8 vf[16];
#pragma unroll
      for (int c = 0; c < 16; ++c)
        vf[c] = *(const f16x8*)(vt_ + c * 1024 + lane * 16);

      // ---- causal mask (final tile only) ----
      if (ti == nt - 1) {
        const int thr = qrow - ti * KT;
#pragma unroll
        for (int kb = 0; kb < 2; ++kb)
#pragma unroll
          for (int r = 0; r < 16; ++r) {
            int kvl = kb * 32 + (r & 3) + 8 * (r >> 2) + 4 * hi;
            if (kvl > thr) s[kb][r] = -1e30f;
          }
      }

      // ---- online softmax with defer-max (T13, THR=8 in log2 units) ----
      float pmax = s[0][0];
#pragma unroll
      for (int r = 1; r < 16; ++r) pmax = fmaxf(pmax, s[0][r]);
#pragma unroll
      for (int r = 0; r < 16; ++r) pmax = fmaxf(pmax, s[1][r]);
      {
        u32x2 pr = swap32(pmax);
        pmax = fmaxf(asf(pr[0]), asf(pr[1]));
      }
      const int need = !__all(pmax <= m_run + 8.0f);
      if (need) {
        const float mn = fmaxf(m_run, pmax);
        const float al = exp2fast(m_run - mn);
        m_run = mn;
#pragma unroll
        for (int r = 0; r < 16; ++r) {
          int row = (r & 3) + 8 * (r >> 2) + 4 * hi;
          float a = __shfl(al, row, 64);
#pragma unroll
          for (int nb = 0; nb < 4; ++nb) acc[nb][r] *= a;
        }
        l_run *= al;
      }
      float rs = 0.f;
#pragma unroll
      for (int kb = 0; kb < 2; ++kb)
#pragma unroll
        for (int r = 0; r < 16; ++r) {
          float p = exp2fast(s[kb][r] - m_run);
          s[kb][r] = p;
          rs += p;
        }
      {
        u32x2 sr = swap32(rs);
        rs = asf(sr[0]) + asf(sr[1]);
      }
      l_run += rs;

      // ---- P -> A-fragments in-register (cvt_pk + permlane32_swap) ----
      f16x8 pa[4];
#pragma unroll
      for (int t = 0; t < 4; ++t) {
        const int kb = t >> 1, rb = (t & 1) * 8;
        unsigned w0 = pkrtz_u(s[kb][rb + 0], s[kb][rb + 1]);
        unsigned w1 = pkrtz_u(s[kb][rb + 2], s[kb][rb + 3]);
        unsigned w2 = pkrtz_u(s[kb][rb + 4], s[kb][rb + 5]);
        unsigned w3 = pkrtz_u(s[kb][rb + 6], s[kb][rb + 7]);
        u32x2 p02 = __builtin_amdgcn_permlane32_swap(w0, w2, false, false);
        u32x2 p13 = __builtin_amdgcn_permlane32_swap(w1, w3, false, false);
        union { unsigned u[4]; f16x8 v; } pw;
        pw.u[0] = p02[0]; pw.u[1] = p13[0]; pw.u[2] = p02[1]; pw.u[3] = p13[1];
        pa[t] = pw.v;
      }

      // ---- O += P V ----
      __builtin_amdgcn_s_setprio(1);
#pragma unroll
      for (int t = 0; t < 4; ++t)
#pragma unroll
        for (int nb = 0; nb < 4; ++nb)
          acc[nb] = __builtin_amdgcn_mfma_f32_32x32x16_f16(pa[t], vf[t * 4 + nb], acc[nb], 0, 0, 0);
      __builtin_amdgcn_s_setprio(0);
    }

    // ---- epilogue: divide by l, coalesced f32 stores ----
    const float linv = 1.0f / l_run;
#pragma unroll
    for (int r = 0; r < 16; ++r) {
      int row = (r & 3) + 8 * (r >> 2) + 4 * hi;
      float li = __shfl(linv, row, 64);
      float* op = og + (size_t)(b * NS + qr0w + row) * (NH * ND) + h * ND + lq;
#pragma unroll
      for (int nb = 0; nb < 4; ++nb)
        op[nb * 32] = acc[nb][r] * li;
    }
  }
}

extern "C" void kernel_launch(void* const* d_in, const int* in_sizes, int n_in,
                              void* d_out, int out_size, void* d_ws, size_t ws_size,
                              hipStream_t stream) {
  const float* q = (const float*)d_in[0];
  const float* k = (const float*)d_in[1];
  const float* v = (const float*)d_in[2];
  float* o = (float*)d_out;

  const size_t KSZ = (size_t)NB * NKV * NS * ND * sizeof(_Float16);  // 16.78 MB each
  if (ws_size < 2 * KSZ) return;     // fail loudly (output stays poisoned)
  char*     wsK = (char*)d_ws;
  _Float16* wsV = (_Float16*)((char*)d_ws + KSZ);

  cvt_kf<<<dim3((NB * NS * 128) / 256), 256, 0, stream>>>(k, wsK);
  cvt_vf<<<dim3(NS / KT, NB, NKV),      256, 0, stream>>>(v, wsV);
  attn_fwd<<<dim3(1024),                256, 0, stream>>>(q, wsK, (const char*)wsV, o);
}